// Round 2
// baseline (738.238 us; speedup 1.0000x reference)
//
#include <hip/hip_runtime.h>
#include <hip/hip_bf16.h>

typedef __hip_bfloat16 bf16;

// flags[0] = 1 if floats are f32 (else bf16); flags[1] = 1 if ints are int64 (else int32)
static __device__ __forceinline__ float loadF(const void* p, long long i, int f32){
  return f32 ? ((const float*)p)[i] : __bfloat162float(((const bf16*)p)[i]);
}
static __device__ __forceinline__ int loadI(const void* p, long long i, int i64){
  return i64 ? (int)((const long long*)p)[i] : ((const int*)p)[i];
}

// ---------------- dtype sniffing ----------------
__global__ void k_sniff(const unsigned int* __restrict__ xw, const unsigned int* __restrict__ eiw,
                        int* __restrict__ flags){
  __shared__ int s1, s2;
  if(threadIdx.x==0){ s1=0; s2=0; }
  __syncthreads();
  // float sniff: for bf16 pairs, (w>>7)&0xFF = exponent of even bf16 elem, clustered ~[110,135]
  // for genuine f32, those are uniform mantissa bits (~10% hit rate)
  unsigned w = xw[threadIdx.x];
  int e = (int)((w>>7)&0xFFu);
  if(e>=110 && e<=135) atomicAdd(&s1, 1);
  // int sniff: int64 values < 2^31 have zero high words at odd int32 positions
  unsigned odd = eiw[2*threadIdx.x+1];
  if(odd != 0u) atomicAdd(&s2, 1);
  __syncthreads();
  if(threadIdx.x==0){
    flags[0] = (s1 < 128) ? 1 : 0;   // 1 => f32
    flags[1] = (s2 < 128) ? 1 : 0;   // 1 => int64
  }
}

// ---------------- degree / dinv ----------------
__global__ void k_deg(const void* __restrict__ ei, int E, int N, const int* __restrict__ flags,
                      int* __restrict__ deg){
  int i64 = flags[1];
  int e = blockIdx.x*256 + threadIdx.x;
  if(e < E){
    int d = loadI(ei, (long long)E + e, i64);
    d = min(max(d,0), N-1);
    atomicAdd(&deg[d], 1);
  }
}

__global__ void k_dinv(const int* __restrict__ deg, int N, float* __restrict__ dinv){
  int i = blockIdx.x*256 + threadIdx.x;
  if(i < N) dinv[i] = rsqrtf((float)(deg[i] + 1));   // +1 self loop, always >= 1
}

// ---------------- prefix scan for CSR row_ptr ----------------
__global__ void k_scan1(const int* __restrict__ deg, int N, int* __restrict__ excl, int* __restrict__ bsum){
  __shared__ int sm[256];
  int tid = threadIdx.x;
  int i = blockIdx.x*256 + tid;
  int v = (i < N) ? deg[i] : 0;
  sm[tid] = v;
  __syncthreads();
  for(int off=1; off<256; off<<=1){
    int t = (tid >= off) ? sm[tid-off] : 0;
    __syncthreads();
    sm[tid] += t;
    __syncthreads();
  }
  if(i < N) excl[i] = sm[tid] - v;
  if(tid == 255) bsum[blockIdx.x] = sm[255];
}

__global__ void k_scan2(int* __restrict__ bsum, int nb){  // nb <= 256
  __shared__ int sm[256];
  int tid = threadIdx.x;
  int v = (tid < nb) ? bsum[tid] : 0;
  sm[tid] = v;
  __syncthreads();
  for(int off=1; off<256; off<<=1){
    int t = (tid >= off) ? sm[tid-off] : 0;
    __syncthreads();
    sm[tid] += t;
    __syncthreads();
  }
  if(tid < nb) bsum[tid] = sm[tid] - v;
}

__global__ void k_scan3(int* __restrict__ rp, const int* __restrict__ bsum, int* __restrict__ cursor,
                        int N, int E){
  int i = blockIdx.x*256 + threadIdx.x;
  if(i < N){ int v = rp[i] + bsum[blockIdx.x]; rp[i] = v; cursor[i] = v; }
  if(i == 0) rp[N] = E;
}

__global__ void k_fill(const void* __restrict__ ei, int E, int N, const int* __restrict__ flags,
                       int* __restrict__ cursor, int* __restrict__ csr){
  int i64 = flags[1];
  int e = blockIdx.x*256 + threadIdx.x;
  if(e < E){
    int s = loadI(ei, e, i64);
    int d = loadI(ei, (long long)E + e, i64);
    s = min(max(s,0), N-1);
    d = min(max(d,0), N-1);
    int j = atomicAdd(&cursor[d], 1);
    if(j < E) csr[j] = s;
  }
}

// ---------------- GEMM1: bufA = (x @ W1) * dinv[row], [N,64] ----------------
__global__ __launch_bounds__(256) void k_gemm1(const void* __restrict__ x, const void* __restrict__ W,
                                               const int* __restrict__ flags,
                                               const float* __restrict__ dinv, float* __restrict__ out, int N){
  __shared__ float Ws[64*64];
  __shared__ float xs[16*64];
  int f32 = flags[0];
  int tid = threadIdx.x;
  for(int i=tid;i<4096;i+=256) Ws[i] = loadF(W, i, f32);
  int row0 = blockIdx.x*16;
  for(int i=tid;i<1024;i+=256){
    int r=i>>6, k=i&63; int gr=row0+r;
    xs[i] = (gr<N) ? loadF(x, (long long)gr*64+k, f32) : 0.f;
  }
  __syncthreads();
  int col = tid&63, rg = tid>>6;
  float acc[4] = {0.f,0.f,0.f,0.f};
  for(int k=0;k<64;k++){
    float w = Ws[k*64+col];
    #pragma unroll
    for(int r=0;r<4;r++) acc[r] += xs[(rg*4+r)*64+k]*w;
  }
  #pragma unroll
  for(int r=0;r<4;r++){
    int gr = row0 + rg*4 + r;
    if(gr<N) out[gr*64+col] = acc[r]*dinv[gr];
  }
}

// ---------------- AGG1: bufB = relu(dinv[d]*(sum nbrs + self) + b1), [N,64] ----------------
__global__ __launch_bounds__(256) void k_agg1(const float* __restrict__ hxs, const int* __restrict__ rp,
                                              const int* __restrict__ csr, const float* __restrict__ dinv,
                                              const void* __restrict__ b, const int* __restrict__ flags,
                                              float* __restrict__ out, int N){
  int f32 = flags[0];
  int node = blockIdx.x*4 + (threadIdx.x>>6);
  int lane = threadIdx.x&63;
  if(node >= N) return;
  float acc = hxs[(long long)node*64+lane];
  int beg = rp[node], end = rp[node+1];
  for(int j=beg;j<end;j++){
    int s = csr[j];
    acc += hxs[(long long)s*64+lane];
  }
  float v = acc*dinv[node] + loadF(b, lane, f32);
  out[(long long)node*64+lane] = v > 0.f ? v : 0.f;
}

// ---------------- GEMM2: bufA = (h1 @ W2) * dinv[row], [N,128] ----------------
__global__ __launch_bounds__(256) void k_gemm2(const float* __restrict__ h1, const void* __restrict__ W,
                                               const int* __restrict__ flags,
                                               const float* __restrict__ dinv, float* __restrict__ out, int N){
  __shared__ float Ws[64*128];
  __shared__ float xs[8*64];
  int f32 = flags[0];
  int tid = threadIdx.x;
  for(int i=tid;i<8192;i+=256) Ws[i] = loadF(W, i, f32);
  int row0 = blockIdx.x*8;
  for(int i=tid;i<512;i+=256){
    int r=i>>6, k=i&63; int gr=row0+r;
    xs[i] = (gr<N) ? h1[(long long)gr*64+k] : 0.f;
  }
  __syncthreads();
  int col = tid&127, rg = tid>>7;
  float acc[4] = {0.f,0.f,0.f,0.f};
  for(int k=0;k<64;k++){
    float w = Ws[k*128+col];
    #pragma unroll
    for(int r=0;r<4;r++) acc[r] += xs[(rg*4+r)*64+k]*w;
  }
  #pragma unroll
  for(int r=0;r<4;r++){
    int gr = row0 + rg*4 + r;
    if(gr<N) out[(long long)gr*128+col] = acc[r]*dinv[gr];
  }
}

// ---------------- AGG2: bufB = relu(dinv[d]*(sum nbrs + self) + b2), [N,128] ----------------
__global__ __launch_bounds__(256) void k_agg2(const float* __restrict__ hys, const int* __restrict__ rp,
                                              const int* __restrict__ csr, const float* __restrict__ dinv,
                                              const void* __restrict__ b, const int* __restrict__ flags,
                                              float* __restrict__ out, int N){
  int f32 = flags[0];
  int node = blockIdx.x*2 + (threadIdx.x>>7);
  int f = threadIdx.x&127;
  if(node >= N) return;
  float acc = hys[(long long)node*128+f];
  int beg = rp[node], end = rp[node+1];
  for(int j=beg;j<end;j++){
    int s = csr[j];
    acc += hys[(long long)s*128+f];
  }
  float v = acc*dinv[node] + loadF(b, f, f32);
  out[(long long)node*128+f] = v > 0.f ? v : 0.f;
}

// ---------------- graph boundaries (batch sorted) ----------------
__global__ void k_bounds(const void* __restrict__ batch, int N, int G, const int* __restrict__ flags,
                         int* __restrict__ gstart){
  int i64 = flags[1];
  int g = blockIdx.x*256 + threadIdx.x;
  if(g > G) return;
  int lo = 0, hi = N;
  while(lo < hi){ int mid = (lo+hi)>>1; if(loadI(batch, mid, i64) < g) lo = mid+1; else hi = mid; }
  gstart[g] = lo;
}

// ---------------- mean pool per graph, [G,128] ----------------
__global__ void k_pool(const float* __restrict__ h2, const int* __restrict__ gstart, float* __restrict__ pooled){
  int g = blockIdx.x; int f = threadIdx.x;          // 128 threads
  int beg = gstart[g], end = gstart[g+1];
  float s = 0.f;
  for(int n=beg;n<end;n++) s += h2[(long long)n*128+f];
  int c = end - beg;
  pooled[g*128+f] = s / (float)(c > 0 ? c : 1);
}

// ---------------- final linear head ----------------
__global__ void k_final(const float* __restrict__ pooled, const void* __restrict__ fcW,
                        const void* __restrict__ fcb, const int* __restrict__ flags,
                        void* __restrict__ out, int G){
  int f32 = flags[0];
  int g = threadIdx.x;
  if(g >= G) return;
  float s = loadF(fcb, 0, f32);
  for(int f=0;f<128;f++) s += pooled[g*128+f]*loadF(fcW, f, f32);
  if(f32) ((float*)out)[g] = s;
  else    ((bf16*)out)[g] = __float2bfloat16(s);
}

extern "C" void kernel_launch(void* const* d_in, const int* in_sizes, int n_in,
                              void* d_out, int out_size, void* d_ws, size_t ws_size,
                              hipStream_t stream) {
  const void* x    = d_in[0];
  const void* ei   = d_in[1];
  const void* batch= d_in[2];
  const void* W1   = d_in[3];
  const void* b1   = d_in[4];
  const void* W2   = d_in[5];
  const void* b2   = d_in[6];
  const void* fcW  = d_in[7];
  const void* fcb  = d_in[8];

  const int N = in_sizes[0] / 64;       // 50000
  const int E = in_sizes[1] / 2;        // 800000
  const int NOUT = in_sizes[8];         // 1
  const int G = out_size / NOUT;        // 128

  // workspace layout (~55.4 MB with bufA/bufB reuse)
  size_t off = 0;
  auto alloc = [&](size_t bytes) -> char* {
    char* p = (char*)d_ws + off;
    off += (bytes + 511) & ~(size_t)511;
    return p;
  };
  int*   flags  = (int*)  alloc(512);
  int*   deg    = (int*)  alloc((size_t)N*4);
  float* dinv   = (float*)alloc((size_t)N*4);
  int*   rp     = (int*)  alloc((size_t)(N+1)*4);
  int*   cursor = (int*)  alloc((size_t)N*4);
  int*   csr    = (int*)  alloc((size_t)E*4);
  int*   bsum   = (int*)  alloc(256*4);
  int*   gstart = (int*)  alloc((size_t)(G+1)*4);
  float* bufA   = (float*)alloc((size_t)N*128*4);   // hxs1 [N,64] then hys2 [N,128]
  float* bufB   = (float*)alloc((size_t)N*128*4);   // h1  [N,64] then h2  [N,128]
  float* pooled = (float*)alloc((size_t)G*128*4);
  (void)ws_size; (void)n_in;

  int nb = (N + 255) / 256;   // 196 <= 256

  k_sniff<<<1, 256, 0, stream>>>((const unsigned int*)x, (const unsigned int*)ei, flags);
  hipMemsetAsync(deg, 0, (size_t)N*4, stream);
  k_deg  <<<(E+255)/256, 256, 0, stream>>>(ei, E, N, flags, deg);
  k_dinv <<<nb,          256, 0, stream>>>(deg, N, dinv);
  k_scan1<<<nb,          256, 0, stream>>>(deg, N, rp, bsum);
  k_scan2<<<1,           256, 0, stream>>>(bsum, nb);
  k_scan3<<<nb,          256, 0, stream>>>(rp, bsum, cursor, N, E);
  k_fill <<<(E+255)/256, 256, 0, stream>>>(ei, E, N, flags, cursor, csr);

  k_gemm1<<<(N+15)/16,   256, 0, stream>>>(x, W1, flags, dinv, bufA, N);
  k_agg1 <<<(N+3)/4,     256, 0, stream>>>(bufA, rp, csr, dinv, b1, flags, bufB, N);
  k_gemm2<<<(N+7)/8,     256, 0, stream>>>(bufB, W2, flags, dinv, bufA, N);
  k_agg2 <<<(N+1)/2,     256, 0, stream>>>(bufA, rp, csr, dinv, b2, flags, bufB, N);

  k_bounds<<<1, 256, 0, stream>>>(batch, N, G, flags, gstart);
  k_pool  <<<G, 128, 0, stream>>>(bufB, gstart, pooled);
  k_final <<<1, G,   0, stream>>>(pooled, fcW, fcb, flags, d_out, G);
}

// Round 3
// 382.010 us; speedup vs baseline: 1.9325x; 1.9325x over previous
//
#include <hip/hip_runtime.h>
#include <hip/hip_bf16.h>

typedef __hip_bfloat16 bf16;

// flags[0] = 1 if floats are f32 (else bf16); flags[1] = 1 if ints are int64 (else int32)
static __device__ __forceinline__ float loadF(const void* p, long long i, int f32){
  return f32 ? ((const float*)p)[i] : __bfloat162float(((const bf16*)p)[i]);
}
static __device__ __forceinline__ int loadI(const void* p, long long i, int i64){
  return i64 ? (int)((const long long*)p)[i] : ((const int*)p)[i];
}

// ---------------- dtype sniffing ----------------
__global__ void k_sniff(const unsigned int* __restrict__ xw, const unsigned int* __restrict__ eiw,
                        int* __restrict__ flags){
  __shared__ int s1, s2;
  if(threadIdx.x==0){ s1=0; s2=0; }
  __syncthreads();
  unsigned w = xw[threadIdx.x];
  int e = (int)((w>>7)&0xFFu);
  if(e>=110 && e<=135) atomicAdd(&s1, 1);
  unsigned odd = eiw[2*threadIdx.x+1];
  if(odd != 0u) atomicAdd(&s2, 1);
  __syncthreads();
  if(threadIdx.x==0){
    flags[0] = (s1 < 128) ? 1 : 0;   // 1 => f32
    flags[1] = (s2 < 128) ? 1 : 0;   // 1 => int64
  }
}

// ---------------- degree ----------------
__global__ void k_deg(const void* __restrict__ ei, int E, int N, const int* __restrict__ flags,
                      int* __restrict__ deg){
  int i64 = flags[1];
  int e = blockIdx.x*256 + threadIdx.x;
  if(e < E){
    int d = loadI(ei, (long long)E + e, i64);
    d = min(max(d,0), N-1);
    atomicAdd(&deg[d], 1);
  }
}

__global__ void k_dinv(const int* __restrict__ deg, int N, float* __restrict__ dinv){
  int i = blockIdx.x*256 + threadIdx.x;
  if(i < N) dinv[i] = rsqrtf((float)(deg[i] + 1));
}

// ---------------- prefix scan for CSR row_ptr ----------------
__global__ void k_scan1(const int* __restrict__ deg, int N, int* __restrict__ excl, int* __restrict__ bsum){
  __shared__ int sm[256];
  int tid = threadIdx.x;
  int i = blockIdx.x*256 + tid;
  int v = (i < N) ? deg[i] : 0;
  sm[tid] = v;
  __syncthreads();
  for(int off=1; off<256; off<<=1){
    int t = (tid >= off) ? sm[tid-off] : 0;
    __syncthreads();
    sm[tid] += t;
    __syncthreads();
  }
  if(i < N) excl[i] = sm[tid] - v;
  if(tid == 255) bsum[blockIdx.x] = sm[255];
}

__global__ void k_scan2(int* __restrict__ bsum, int nb){  // nb <= 256
  __shared__ int sm[256];
  int tid = threadIdx.x;
  int v = (tid < nb) ? bsum[tid] : 0;
  sm[tid] = v;
  __syncthreads();
  for(int off=1; off<256; off<<=1){
    int t = (tid >= off) ? sm[tid-off] : 0;
    __syncthreads();
    sm[tid] += t;
    __syncthreads();
  }
  if(tid < nb) bsum[tid] = sm[tid] - v;
}

__global__ void k_scan3(int* __restrict__ rp, const int* __restrict__ bsum, int* __restrict__ cursor,
                        int N, int E){
  int i = blockIdx.x*256 + threadIdx.x;
  if(i < N){ int v = rp[i] + bsum[blockIdx.x]; rp[i] = v; cursor[i] = v; }
  if(i == 0) rp[N] = E;
}

__global__ void k_fill(const void* __restrict__ ei, int E, int N, const int* __restrict__ flags,
                       int* __restrict__ cursor, int* __restrict__ csr){
  int i64 = flags[1];
  int e = blockIdx.x*256 + threadIdx.x;
  if(e < E){
    int s = loadI(ei, e, i64);
    int d = loadI(ei, (long long)E + e, i64);
    s = min(max(s,0), N-1);
    d = min(max(d,0), N-1);
    int j = atomicAdd(&cursor[d], 1);
    if(j < E) csr[j] = s;
  }
}

// ---------------- GEMM1: out = (x @ W1) * dinv[row], [N,64] ----------------
// tile: 128 rows x 64 cols, 256 threads, R=8 rows C=4 cols per thread
__global__ __launch_bounds__(256) void k_gemm1(const void* __restrict__ x, const void* __restrict__ W,
                                               const int* __restrict__ flags,
                                               const float* __restrict__ dinv, float* __restrict__ out, int N){
  __shared__ float Ws[64*64];        // 16 KB
  __shared__ float xs[128*65];       // 33.25 KB, stride 65 kills bank conflicts
  int f32 = flags[0];
  int tid = threadIdx.x;
  for(int i=tid;i<4096;i+=256) Ws[i] = loadF(W, i, f32);
  int row0 = blockIdx.x*128;
  for(int i=tid;i<8192;i+=256){
    int r=i>>6, k=i&63; int gr=row0+r;
    xs[r*65+k] = (gr<N) ? loadF(x, (long long)gr*64+k, f32) : 0.f;
  }
  __syncthreads();
  int cg = tid&15, rg = tid>>4;      // col_g = cg*4, row_g = rg*8
  int col_g = cg*4, row_g = rg*8;
  float acc[8][4];
  #pragma unroll
  for(int r=0;r<8;r++){ acc[r][0]=0.f; acc[r][1]=0.f; acc[r][2]=0.f; acc[r][3]=0.f; }
  for(int k=0;k<64;k++){
    float4 w = *(const float4*)&Ws[k*64 + col_g];
    float xr[8];
    #pragma unroll
    for(int r=0;r<8;r++) xr[r] = xs[(row_g+r)*65 + k];
    #pragma unroll
    for(int r=0;r<8;r++){
      acc[r][0] += xr[r]*w.x; acc[r][1] += xr[r]*w.y;
      acc[r][2] += xr[r]*w.z; acc[r][3] += xr[r]*w.w;
    }
  }
  #pragma unroll
  for(int r=0;r<8;r++){
    int gr = row0 + row_g + r;
    if(gr<N){
      float dv = dinv[gr];
      float4 st = make_float4(acc[r][0]*dv, acc[r][1]*dv, acc[r][2]*dv, acc[r][3]*dv);
      *(float4*)&out[(long long)gr*64 + col_g] = st;
    }
  }
}

// ---------------- AGG1: relu(dinv[d]*(sum nbrs + self) + b1), [N,64] ----------------
__global__ __launch_bounds__(256) void k_agg1(const float* __restrict__ hxs, const int* __restrict__ rp,
                                              const int* __restrict__ csr, const float* __restrict__ dinv,
                                              const void* __restrict__ b, const int* __restrict__ flags,
                                              float* __restrict__ out, int N){
  int f32 = flags[0];
  int node = blockIdx.x*4 + (threadIdx.x>>6);
  int lane = threadIdx.x&63;
  if(node >= N) return;
  int beg = rp[node], end = rp[node+1];
  float a0=0.f, a1=0.f, a2=0.f, a3=0.f;
  int j = beg;
  for(; j+4<=end; j+=4){
    int s0=csr[j], s1=csr[j+1], s2=csr[j+2], s3=csr[j+3];
    a0 += hxs[(long long)s0*64+lane];
    a1 += hxs[(long long)s1*64+lane];
    a2 += hxs[(long long)s2*64+lane];
    a3 += hxs[(long long)s3*64+lane];
  }
  for(; j<end; j++) a0 += hxs[(long long)csr[j]*64+lane];
  float acc = hxs[(long long)node*64+lane] + ((a0+a1)+(a2+a3));
  float v = acc*dinv[node] + loadF(b, lane, f32);
  out[(long long)node*64+lane] = v > 0.f ? v : 0.f;
}

// ---------------- GEMM2: out = (h1 @ W2) * dinv[row], [N,128] ----------------
// tile: 64 rows x 128 cols, 256 threads, R=4 rows C=8 cols per thread
__global__ __launch_bounds__(256) void k_gemm2(const float* __restrict__ h1, const void* __restrict__ W,
                                               const int* __restrict__ flags,
                                               const float* __restrict__ dinv, float* __restrict__ out, int N){
  __shared__ float Ws[64*128];       // 32 KB
  __shared__ float xs[64*65];        // 16.6 KB
  int f32 = flags[0];
  int tid = threadIdx.x;
  for(int i=tid;i<8192;i+=256) Ws[i] = loadF(W, i, f32);
  int row0 = blockIdx.x*64;
  for(int i=tid;i<4096;i+=256){
    int r=i>>6, k=i&63; int gr=row0+r;
    xs[r*65+k] = (gr<N) ? h1[(long long)gr*64+k] : 0.f;
  }
  __syncthreads();
  int cg = tid&15, rg = tid>>4;      // col_g = cg*8, row_g = rg*4
  int col_g = cg*8, row_g = rg*4;
  float acc[4][8];
  #pragma unroll
  for(int r=0;r<4;r++)
    #pragma unroll
    for(int c=0;c<8;c++) acc[r][c]=0.f;
  for(int k=0;k<64;k++){
    float4 w0 = *(const float4*)&Ws[k*128 + col_g];
    float4 w1 = *(const float4*)&Ws[k*128 + col_g + 4];
    float xr[4];
    #pragma unroll
    for(int r=0;r<4;r++) xr[r] = xs[(row_g+r)*65 + k];
    #pragma unroll
    for(int r=0;r<4;r++){
      acc[r][0] += xr[r]*w0.x; acc[r][1] += xr[r]*w0.y;
      acc[r][2] += xr[r]*w0.z; acc[r][3] += xr[r]*w0.w;
      acc[r][4] += xr[r]*w1.x; acc[r][5] += xr[r]*w1.y;
      acc[r][6] += xr[r]*w1.z; acc[r][7] += xr[r]*w1.w;
    }
  }
  #pragma unroll
  for(int r=0;r<4;r++){
    int gr = row0 + row_g + r;
    if(gr<N){
      float dv = dinv[gr];
      float4 s0 = make_float4(acc[r][0]*dv, acc[r][1]*dv, acc[r][2]*dv, acc[r][3]*dv);
      float4 s1 = make_float4(acc[r][4]*dv, acc[r][5]*dv, acc[r][6]*dv, acc[r][7]*dv);
      *(float4*)&out[(long long)gr*128 + col_g]     = s0;
      *(float4*)&out[(long long)gr*128 + col_g + 4] = s1;
    }
  }
}

// ---------------- AGG2: relu(dinv[d]*(sum nbrs + self) + b2), [N,128] ----------------
// one node per 64-lane wave, float2 per lane
__global__ __launch_bounds__(256) void k_agg2(const float* __restrict__ hys, const int* __restrict__ rp,
                                              const int* __restrict__ csr, const float* __restrict__ dinv,
                                              const void* __restrict__ b, const int* __restrict__ flags,
                                              float* __restrict__ out, int N){
  int f32 = flags[0];
  int node = blockIdx.x*4 + (threadIdx.x>>6);
  int lane = threadIdx.x&63;
  if(node >= N) return;
  const float2* H = (const float2*)hys;
  int beg = rp[node], end = rp[node+1];
  float2 a0={0.f,0.f}, a1={0.f,0.f}, a2={0.f,0.f}, a3={0.f,0.f};
  int j = beg;
  for(; j+4<=end; j+=4){
    int s0=csr[j], s1=csr[j+1], s2=csr[j+2], s3=csr[j+3];
    float2 v0 = H[(long long)s0*64+lane];
    float2 v1 = H[(long long)s1*64+lane];
    float2 v2 = H[(long long)s2*64+lane];
    float2 v3 = H[(long long)s3*64+lane];
    a0.x += v0.x; a0.y += v0.y;
    a1.x += v1.x; a1.y += v1.y;
    a2.x += v2.x; a2.y += v2.y;
    a3.x += v3.x; a3.y += v3.y;
  }
  for(; j<end; j++){
    float2 v = H[(long long)csr[j]*64+lane];
    a0.x += v.x; a0.y += v.y;
  }
  float2 self = H[(long long)node*64+lane];
  float sx = self.x + ((a0.x+a1.x)+(a2.x+a3.x));
  float sy = self.y + ((a0.y+a1.y)+(a2.y+a3.y));
  float dv = dinv[node];
  float bx = loadF(b, lane*2,   f32);
  float by = loadF(b, lane*2+1, f32);
  float vx = sx*dv + bx;
  float vy = sy*dv + by;
  float2 st = make_float2(vx > 0.f ? vx : 0.f, vy > 0.f ? vy : 0.f);
  *(float2*)&out[(long long)node*128 + lane*2] = st;
}

// ---------------- graph boundaries (batch sorted) ----------------
__global__ void k_bounds(const void* __restrict__ batch, int N, int G, const int* __restrict__ flags,
                         int* __restrict__ gstart){
  int i64 = flags[1];
  int g = blockIdx.x*256 + threadIdx.x;
  if(g > G) return;
  int lo = 0, hi = N;
  while(lo < hi){ int mid = (lo+hi)>>1; if(loadI(batch, mid, i64) < g) lo = mid+1; else hi = mid; }
  gstart[g] = lo;
}

// ---------------- mean pool per graph, [G,128] ----------------
__global__ void k_pool(const float* __restrict__ h2, const int* __restrict__ gstart, float* __restrict__ pooled){
  int g = blockIdx.x; int f = threadIdx.x;          // 128 threads
  int beg = gstart[g], end = gstart[g+1];
  float a0=0.f, a1=0.f, a2=0.f, a3=0.f;
  int n = beg;
  for(; n+4<=end; n+=4){
    a0 += h2[(long long)(n  )*128+f];
    a1 += h2[(long long)(n+1)*128+f];
    a2 += h2[(long long)(n+2)*128+f];
    a3 += h2[(long long)(n+3)*128+f];
  }
  for(; n<end; n++) a0 += h2[(long long)n*128+f];
  float s = (a0+a1)+(a2+a3);
  int c = end - beg;
  pooled[g*128+f] = s / (float)(c > 0 ? c : 1);
}

// ---------------- final linear head ----------------
__global__ void k_final(const float* __restrict__ pooled, const void* __restrict__ fcW,
                        const void* __restrict__ fcb, const int* __restrict__ flags,
                        void* __restrict__ out, int G){
  int f32 = flags[0];
  int g = threadIdx.x;
  if(g >= G) return;
  float s = loadF(fcb, 0, f32);
  for(int f=0;f<128;f++) s += pooled[g*128+f]*loadF(fcW, f, f32);
  if(f32) ((float*)out)[g] = s;
  else    ((bf16*)out)[g] = __float2bfloat16(s);
}

extern "C" void kernel_launch(void* const* d_in, const int* in_sizes, int n_in,
                              void* d_out, int out_size, void* d_ws, size_t ws_size,
                              hipStream_t stream) {
  const void* x    = d_in[0];
  const void* ei   = d_in[1];
  const void* batch= d_in[2];
  const void* W1   = d_in[3];
  const void* b1   = d_in[4];
  const void* W2   = d_in[5];
  const void* b2   = d_in[6];
  const void* fcW  = d_in[7];
  const void* fcb  = d_in[8];

  const int N = in_sizes[0] / 64;       // 50000
  const int E = in_sizes[1] / 2;        // 800000
  const int NOUT = in_sizes[8];         // 1
  const int G = out_size / NOUT;        // 128

  size_t off = 0;
  auto alloc = [&](size_t bytes) -> char* {
    char* p = (char*)d_ws + off;
    off += (bytes + 511) & ~(size_t)511;
    return p;
  };
  int*   flags  = (int*)  alloc(512);
  int*   deg    = (int*)  alloc((size_t)N*4);
  float* dinv   = (float*)alloc((size_t)N*4);
  int*   rp     = (int*)  alloc((size_t)(N+1)*4);
  int*   cursor = (int*)  alloc((size_t)N*4);
  int*   csr    = (int*)  alloc((size_t)E*4);
  int*   bsum   = (int*)  alloc(256*4);
  int*   gstart = (int*)  alloc((size_t)(G+1)*4);
  float* bufA   = (float*)alloc((size_t)N*128*4);   // hxs1 [N,64] then hys2 [N,128]
  float* bufB   = (float*)alloc((size_t)N*128*4);   // h1  [N,64] then h2  [N,128]
  float* pooled = (float*)alloc((size_t)G*128*4);
  (void)ws_size; (void)n_in;

  int nb = (N + 255) / 256;

  k_sniff<<<1, 256, 0, stream>>>((const unsigned int*)x, (const unsigned int*)ei, flags);
  hipMemsetAsync(deg, 0, (size_t)N*4, stream);
  k_deg  <<<(E+255)/256, 256, 0, stream>>>(ei, E, N, flags, deg);
  k_dinv <<<nb,          256, 0, stream>>>(deg, N, dinv);
  k_scan1<<<nb,          256, 0, stream>>>(deg, N, rp, bsum);
  k_scan2<<<1,           256, 0, stream>>>(bsum, nb);
  k_scan3<<<nb,          256, 0, stream>>>(rp, bsum, cursor, N, E);
  k_fill <<<(E+255)/256, 256, 0, stream>>>(ei, E, N, flags, cursor, csr);

  k_gemm1<<<(N+127)/128, 256, 0, stream>>>(x, W1, flags, dinv, bufA, N);
  k_agg1 <<<(N+3)/4,     256, 0, stream>>>(bufA, rp, csr, dinv, b1, flags, bufB, N);
  k_gemm2<<<(N+63)/64,   256, 0, stream>>>(bufB, W2, flags, dinv, bufA, N);
  k_agg2 <<<(N+3)/4,     256, 0, stream>>>(bufA, rp, csr, dinv, b2, flags, bufB, N);

  k_bounds<<<1, 256, 0, stream>>>(batch, N, G, flags, gstart);
  k_pool  <<<G, 128, 0, stream>>>(bufB, gstart, pooled);
  k_final <<<1, G,   0, stream>>>(pooled, fcW, fcb, flags, d_out, G);
}

// Round 5
// 351.783 us; speedup vs baseline: 2.0986x; 1.0859x over previous
//
#include <hip/hip_runtime.h>
#include <hip/hip_bf16.h>

typedef __hip_bfloat16 bf16;

// flags[0] = 1 if floats are f32 (else bf16); flags[1] = 1 if ints are int64 (else int32)
static __device__ __forceinline__ float loadF(const void* p, long long i, int f32){
  return f32 ? ((const float*)p)[i] : __bfloat162float(((const bf16*)p)[i]);
}
static __device__ __forceinline__ int loadI(const void* p, long long i, int i64){
  return i64 ? (int)((const long long*)p)[i] : ((const int*)p)[i];
}
// round-to-nearest-even float -> bf16 bits (finite inputs)
static __device__ __forceinline__ unsigned short f2bf(float f){
  unsigned u = __float_as_uint(f);
  return (unsigned short)((u + 0x7FFFu + ((u>>16)&1u)) >> 16);
}

// ---------------- init: zero deg (whole grid) + dtype sniff (block 0) ----------------
__global__ void k_init(const unsigned int* __restrict__ xw, const unsigned int* __restrict__ eiw,
                       int* __restrict__ flags, int* __restrict__ deg, int N){
  int i = blockIdx.x*256 + threadIdx.x;
  if(i < N) deg[i] = 0;
  if(blockIdx.x == 0){
    __shared__ int s1, s2;
    if(threadIdx.x==0){ s1=0; s2=0; }
    __syncthreads();
    unsigned w = xw[threadIdx.x];
    int e = (int)((w>>7)&0xFFu);
    if(e>=110 && e<=135) atomicAdd(&s1, 1);      // bf16-pair exponent signature
    if(eiw[2*threadIdx.x+1] != 0u) atomicAdd(&s2, 1);  // int64 high words
    __syncthreads();
    if(threadIdx.x==0){
      flags[0] = (s1 < 128) ? 1 : 0;   // 1 => f32
      flags[1] = (s2 < 128) ? 1 : 0;   // 1 => int64
    }
  }
}

// ---------------- degree ----------------
__global__ void k_deg(const void* __restrict__ ei, int E, int N, const int* __restrict__ flags,
                      int* __restrict__ deg){
  int i64 = flags[1];
  int e = blockIdx.x*256 + threadIdx.x;
  if(e < E){
    int d = loadI(ei, (long long)E + e, i64);
    d = min(max(d,0), N-1);
    atomicAdd(&deg[d], 1);
  }
}

// ---------------- prefix scan for CSR row_ptr (+ dinv fused) ----------------
__global__ void k_scan1(const int* __restrict__ deg, int N, int* __restrict__ excl, int* __restrict__ bsum,
                        float* __restrict__ dinv){
  __shared__ int sm[256];
  int tid = threadIdx.x;
  int i = blockIdx.x*256 + tid;
  int v = (i < N) ? deg[i] : 0;
  if(i < N) dinv[i] = rsqrtf((float)(v + 1));    // +1 = self loop
  sm[tid] = v;
  __syncthreads();
  for(int off=1; off<256; off<<=1){
    int t = (tid >= off) ? sm[tid-off] : 0;
    __syncthreads();
    sm[tid] += t;
    __syncthreads();
  }
  if(i < N) excl[i] = sm[tid] - v;
  if(tid == 255) bsum[blockIdx.x] = sm[255];
}

__global__ void k_scan2(int* __restrict__ bsum, int nb){  // nb <= 256
  __shared__ int sm[256];
  int tid = threadIdx.x;
  int v = (tid < nb) ? bsum[tid] : 0;
  sm[tid] = v;
  __syncthreads();
  for(int off=1; off<256; off<<=1){
    int t = (tid >= off) ? sm[tid-off] : 0;
    __syncthreads();
    sm[tid] += t;
    __syncthreads();
  }
  if(tid < nb) bsum[tid] = sm[tid] - v;
}

__global__ void k_scan3(int* __restrict__ rp, const int* __restrict__ bsum, int* __restrict__ cursor,
                        int N, int E){
  int i = blockIdx.x*256 + threadIdx.x;
  if(i < N){ int v = rp[i] + bsum[blockIdx.x]; rp[i] = v; cursor[i] = v; }
  if(i == 0) rp[N] = E;
}

__global__ void k_fill(const void* __restrict__ ei, int E, int N, const int* __restrict__ flags,
                       int* __restrict__ cursor, int* __restrict__ csr){
  int i64 = flags[1];
  int e = blockIdx.x*256 + threadIdx.x;
  if(e < E){
    int s = loadI(ei, e, i64);
    int d = loadI(ei, (long long)E + e, i64);
    s = min(max(s,0), N-1);
    d = min(max(d,0), N-1);
    int j = atomicAdd(&cursor[d], 1);
    if(j < E) csr[j] = s;
  }
}

// ---------------- g0 = bf16(x * dinv[node]), [N,64] ----------------
__global__ void k_g0(const void* __restrict__ x, const float* __restrict__ dinv,
                     const int* __restrict__ flags, unsigned short* __restrict__ g0, long long total){
  int f32 = flags[0];
  long long i = (long long)blockIdx.x*256 + threadIdx.x;
  if(i < total){
    int node = (int)(i >> 6);
    g0[i] = f2bf(loadF(x, i, f32) * dinv[node]);
  }
}

// ---------------- AGG: a[d] = dinv[d] * (sum_{s in N(d)} g[s] + g[d]), 64 feats bf16->f32 ----------------
__global__ __launch_bounds__(256) void k_agg(const bf16* __restrict__ g, const int* __restrict__ rp,
                                             const int* __restrict__ csr, const float* __restrict__ dinv,
                                             float* __restrict__ out, int N){
  int node = blockIdx.x*4 + (threadIdx.x>>6);
  int lane = threadIdx.x&63;
  if(node >= N) return;
  int beg = rp[node], end = rp[node+1];
  float a0=0.f, a1=0.f, a2=0.f, a3=0.f;
  int j = beg;
  for(; j+4<=end; j+=4){
    int s0=csr[j], s1=csr[j+1], s2=csr[j+2], s3=csr[j+3];
    a0 += __bfloat162float(g[(long long)s0*64+lane]);
    a1 += __bfloat162float(g[(long long)s1*64+lane]);
    a2 += __bfloat162float(g[(long long)s2*64+lane]);
    a3 += __bfloat162float(g[(long long)s3*64+lane]);
  }
  for(; j<end; j++) a0 += __bfloat162float(g[(long long)csr[j]*64+lane]);
  float acc = __bfloat162float(g[(long long)node*64+lane]) + ((a0+a1)+(a2+a3));
  out[(long long)node*64+lane] = acc*dinv[node];
}

// ---------------- GEMM1: g1 = bf16(relu(a @ W1 + b1) * dinv[row]), [N,64] ----------------
// tile: 128 rows x 64 cols, 256 threads, R=8 C=4 per thread
__global__ __launch_bounds__(256) void k_gemm1(const float* __restrict__ a, const void* __restrict__ W,
                                               const void* __restrict__ b, const int* __restrict__ flags,
                                               const float* __restrict__ dinv, unsigned short* __restrict__ out, int N){
  __shared__ float Ws[64*64];
  __shared__ float xs[128*65];
  int f32 = flags[0];
  int tid = threadIdx.x;
  for(int i=tid;i<4096;i+=256) Ws[i] = loadF(W, i, f32);
  int row0 = blockIdx.x*128;
  for(int i=tid;i<8192;i+=256){
    int r=i>>6, k=i&63; int gr=row0+r;
    xs[r*65+k] = (gr<N) ? a[(long long)gr*64+k] : 0.f;
  }
  __syncthreads();
  int cg = tid&15, rg = tid>>4;
  int col_g = cg*4, row_g = rg*8;
  float acc[8][4];
  #pragma unroll
  for(int r=0;r<8;r++){ acc[r][0]=0.f; acc[r][1]=0.f; acc[r][2]=0.f; acc[r][3]=0.f; }
  for(int k=0;k<64;k++){
    float4 w = *(const float4*)&Ws[k*64 + col_g];
    float xr[8];
    #pragma unroll
    for(int r=0;r<8;r++) xr[r] = xs[(row_g+r)*65 + k];
    #pragma unroll
    for(int r=0;r<8;r++){
      acc[r][0] += xr[r]*w.x; acc[r][1] += xr[r]*w.y;
      acc[r][2] += xr[r]*w.z; acc[r][3] += xr[r]*w.w;
    }
  }
  float b0 = loadF(b, col_g,   f32), b1v = loadF(b, col_g+1, f32);
  float b2v = loadF(b, col_g+2, f32), b3 = loadF(b, col_g+3, f32);
  #pragma unroll
  for(int r=0;r<8;r++){
    int gr = row0 + row_g + r;
    if(gr<N){
      float dv = dinv[gr];
      float v0 = acc[r][0]+b0, v1 = acc[r][1]+b1v, v2 = acc[r][2]+b2v, v3 = acc[r][3]+b3;
      v0 = (v0>0.f?v0:0.f)*dv; v1 = (v1>0.f?v1:0.f)*dv;
      v2 = (v2>0.f?v2:0.f)*dv; v3 = (v3>0.f?v3:0.f)*dv;
      ushort4 st;
      st.x = f2bf(v0); st.y = f2bf(v1); st.z = f2bf(v2); st.w = f2bf(v3);
      *(ushort4*)&out[(long long)gr*64 + col_g] = st;
    }
  }
}

// ---------------- GEMM2: h2 = relu(a @ W2 + b2), [N,128] f32 ----------------
// tile: 64 rows x 128 cols, 256 threads, R=4 C=8 per thread
__global__ __launch_bounds__(256) void k_gemm2(const float* __restrict__ a, const void* __restrict__ W,
                                               const void* __restrict__ b, const int* __restrict__ flags,
                                               float* __restrict__ out, int N){
  __shared__ float Ws[64*128];
  __shared__ float xs[64*65];
  int f32 = flags[0];
  int tid = threadIdx.x;
  for(int i=tid;i<8192;i+=256) Ws[i] = loadF(W, i, f32);
  int row0 = blockIdx.x*64;
  for(int i=tid;i<4096;i+=256){
    int r=i>>6, k=i&63; int gr=row0+r;
    xs[r*65+k] = (gr<N) ? a[(long long)gr*64+k] : 0.f;
  }
  __syncthreads();
  int cg = tid&15, rg = tid>>4;
  int col_g = cg*8, row_g = rg*4;
  float acc[4][8];
  #pragma unroll
  for(int r=0;r<4;r++)
    #pragma unroll
    for(int c=0;c<8;c++) acc[r][c]=0.f;
  for(int k=0;k<64;k++){
    float4 w0 = *(const float4*)&Ws[k*128 + col_g];
    float4 w1 = *(const float4*)&Ws[k*128 + col_g + 4];
    float xr[4];
    #pragma unroll
    for(int r=0;r<4;r++) xr[r] = xs[(row_g+r)*65 + k];
    #pragma unroll
    for(int r=0;r<4;r++){
      acc[r][0] += xr[r]*w0.x; acc[r][1] += xr[r]*w0.y;
      acc[r][2] += xr[r]*w0.z; acc[r][3] += xr[r]*w0.w;
      acc[r][4] += xr[r]*w1.x; acc[r][5] += xr[r]*w1.y;
      acc[r][6] += xr[r]*w1.z; acc[r][7] += xr[r]*w1.w;
    }
  }
  float bb[8];
  #pragma unroll
  for(int c=0;c<8;c++) bb[c] = loadF(b, col_g+c, f32);
  #pragma unroll
  for(int r=0;r<4;r++){
    int gr = row0 + row_g + r;
    if(gr<N){
      float v[8];
      #pragma unroll
      for(int c=0;c<8;c++){ float z = acc[r][c]+bb[c]; v[c] = z>0.f?z:0.f; }
      *(float4*)&out[(long long)gr*128 + col_g]     = make_float4(v[0],v[1],v[2],v[3]);
      *(float4*)&out[(long long)gr*128 + col_g + 4] = make_float4(v[4],v[5],v[6],v[7]);
    }
  }
}

// ---------------- fused mean-pool + linear head ----------------
static __device__ __forceinline__ int lower_bound_batch(const void* batch, int N, int key, int i64){
  int lo = 0, hi = N;
  while(lo < hi){ int mid = (lo+hi)>>1; if(loadI(batch, mid, i64) < key) lo = mid+1; else hi = mid; }
  return lo;
}

__global__ void k_poolfinal(const float* __restrict__ h2, const void* __restrict__ batch, int N,
                            const int* __restrict__ flags, const void* __restrict__ fcW,
                            const void* __restrict__ fcb, void* __restrict__ out, int NOUT){
  int f32 = flags[0], i64 = flags[1];
  int g = blockIdx.x; int f = threadIdx.x;          // 128 threads
  int beg = lower_bound_batch(batch, N, g,   i64);
  int end = lower_bound_batch(batch, N, g+1, i64);
  float a0=0.f, a1=0.f, a2=0.f, a3=0.f;
  int n = beg;
  for(; n+4<=end; n+=4){
    a0 += h2[(long long)(n  )*128+f];
    a1 += h2[(long long)(n+1)*128+f];
    a2 += h2[(long long)(n+2)*128+f];
    a3 += h2[(long long)(n+3)*128+f];
  }
  for(; n<end; n++) a0 += h2[(long long)n*128+f];
  int c = end - beg;
  float pooled = ((a0+a1)+(a2+a3)) / (float)(c > 0 ? c : 1);
  __shared__ float sm[128];
  for(int o=0;o<NOUT;o++){
    sm[f] = pooled * loadF(fcW, (long long)f*NOUT+o, f32);
    __syncthreads();
    for(int s=64;s>0;s>>=1){
      if(f < s) sm[f] += sm[f+s];
      __syncthreads();
    }
    if(f==0){
      float r = sm[0] + loadF(fcb, o, f32);
      if(f32) ((float*)out)[g*NOUT+o] = r;
      else    ((unsigned short*)out)[g*NOUT+o] = f2bf(r);
    }
    __syncthreads();
  }
}

extern "C" void kernel_launch(void* const* d_in, const int* in_sizes, int n_in,
                              void* d_out, int out_size, void* d_ws, size_t ws_size,
                              hipStream_t stream) {
  const void* x    = d_in[0];
  const void* ei   = d_in[1];
  const void* batch= d_in[2];
  const void* W1   = d_in[3];
  const void* b1   = d_in[4];
  const void* W2   = d_in[5];
  const void* b2   = d_in[6];
  const void* fcW  = d_in[7];
  const void* fcb  = d_in[8];

  const int N = in_sizes[0] / 64;       // 50000
  const int E = in_sizes[1] / 2;        // 800000
  const int NOUT = in_sizes[8];         // 1
  const int G = out_size / NOUT;        // 128

  size_t off = 0;
  auto alloc = [&](size_t bytes) -> char* {
    char* p = (char*)d_ws + off;
    off += (bytes + 511) & ~(size_t)511;
    return p;
  };
  int*   flags  = (int*)  alloc(512);
  int*   deg    = (int*)  alloc((size_t)N*4);
  float* dinv   = (float*)alloc((size_t)N*4);
  int*   rp     = (int*)  alloc((size_t)(N+1)*4);
  int*   cursor = (int*)  alloc((size_t)N*4);
  int*   csr    = (int*)  alloc((size_t)E*4);
  int*   bsum   = (int*)  alloc(256*4);
  unsigned short* g0 = (unsigned short*)alloc((size_t)N*64*2);   // 6.4 MB
  unsigned short* g1 = (unsigned short*)alloc((size_t)N*64*2);   // 6.4 MB
  float* aB     = (float*)alloc((size_t)N*64*4);    // 12.8 MB (a1 then a2)
  float* h2     = (float*)alloc((size_t)N*128*4);   // 25.6 MB
  (void)ws_size; (void)n_in;

  int nb = (N + 255) / 256;             // 196 <= 256
  long long total0 = (long long)N*64;

  k_init <<<nb,          256, 0, stream>>>((const unsigned int*)x, (const unsigned int*)ei, flags, deg, N);
  k_deg  <<<(E+255)/256, 256, 0, stream>>>(ei, E, N, flags, deg);
  k_scan1<<<nb,          256, 0, stream>>>(deg, N, rp, bsum, dinv);
  k_scan2<<<1,           256, 0, stream>>>(bsum, nb);
  k_scan3<<<nb,          256, 0, stream>>>(rp, bsum, cursor, N, E);
  k_fill <<<(E+255)/256, 256, 0, stream>>>(ei, E, N, flags, cursor, csr);

  k_g0   <<<(int)((total0+255)/256), 256, 0, stream>>>(x, dinv, flags, g0, total0);
  k_agg  <<<(N+3)/4,     256, 0, stream>>>((const bf16*)g0, rp, csr, dinv, aB, N);        // a1
  k_gemm1<<<(N+127)/128, 256, 0, stream>>>(aB, W1, b1, flags, dinv, g1, N);               // g1
  k_agg  <<<(N+3)/4,     256, 0, stream>>>((const bf16*)g1, rp, csr, dinv, aB, N);        // a2
  k_gemm2<<<(N+63)/64,   256, 0, stream>>>(aB, W2, b2, flags, h2, N);                     // h2

  k_poolfinal<<<G, 128, 0, stream>>>(h2, batch, N, flags, fcW, fcb, d_out, NOUT);
}